// Round 1
// baseline (298.537 us; speedup 1.0000x reference)
//
#include <hip/hip_runtime.h>
#include <hip/hip_bf16.h>

#define B_TOK 8192
#define D_DIM 3072
#define H_DIM 128
#define O_DIM 10
#define N_EXP 8

#define BM 128
#define BK2 128            // K-tile (24 iters over D=3072)
#define HLDS_STRIDE 136    // bf16 elems; row byte stride 272
#define CHK 768            // k1a D-chunk
#define NCHK 4
#define ESTRIDE 4096       // static slots per expert (>25 sigma above mean 2048)

#define K1A_BLOCKS 1024    // (B_TOK/32) * NCHK = 256*4
#define K0_BLOCKS  768     // 48 * 2 * 8

typedef __bf16 bf16x8 __attribute__((ext_vector_type(8)));
typedef float  f32x4  __attribute__((ext_vector_type(4)));
typedef unsigned short us8 __attribute__((ext_vector_type(8)));

// fp32 -> bf16 round-to-nearest-even
__device__ __forceinline__ unsigned short f2bf(float f) {
  unsigned int u = __float_as_uint(f);
  unsigned int r = (u + 0x7FFFu + ((u >> 16) & 1u)) >> 16;
  return (unsigned short)r;
}

__device__ __forceinline__ void async16(const void* g, void* l) {
  __builtin_amdgcn_global_load_lds(
      (const __attribute__((address_space(1))) void*)g,
      (__attribute__((address_space(3))) void*)l,
      16, 0, 0);
}

// ---------------- K01 fused: [blocks 0..1023] x->bf16 + partial gating
//                  [blocks 1024..1791] W1 [8][3072][128] fp32 -> W1^T bf16 ----------------
// k1a part: 32 tokens/block (2 groups of 16), Wg tile staged once per block.
// k0 part rides at the grid tail: its light blocks fill CUs as k1a blocks drain.
__global__ __launch_bounds__(256, 4) void k01_fused(
    const float* __restrict__ x, const float* __restrict__ Wg,
    unsigned short* __restrict__ xb, float* __restrict__ gpart,
    const float* __restrict__ W1, unsigned short* __restrict__ w1t) {
  __shared__ __align__(16) char smem[N_EXP * CHK * 4];  // 24 KB (>= k0's 9.2 KB)
  const int tid = threadIdx.x;

  if (blockIdx.x >= K1A_BLOCKS) {
    // ---- k0 path: W1 transpose ----
    unsigned short* lds = (unsigned short*)smem;  // [64][72]
    const int id = blockIdx.x - K1A_BLOCKS;
    const int e  = id / 96;
    const int r  = id - e * 96;
    const int h0 = (r / 48) * 64;
    const int d0 = (r % 48) * 64;

    const float* src = W1 + ((size_t)e * D_DIM + d0) * H_DIM + h0;
    const int hl = tid & 63;   // h lane
    const int dg = tid >> 6;   // 0..3
#pragma unroll
    for (int k = 0; k < 16; ++k) {
      const int d = dg + 4 * k;
      lds[hl * 72 + d] = f2bf(src[(size_t)d * H_DIM + hl]);
    }
    __syncthreads();

    unsigned short* dst = w1t + ((size_t)e * H_DIM + h0) * D_DIM + d0;
    const int q  = tid & 7;    // d-oct
    const int h1 = tid >> 3;   // 0..31
#pragma unroll
    for (int k = 0; k < 2; ++k) {
      const int h = h1 + 32 * k;
      const int d = q * 8;
      us8 v = *(const us8*)(lds + h * 72 + d);
      *(us8*)(dst + (size_t)h * D_DIM + d) = v;
    }
    return;
  }

  // ---- k1a path: stream x -> bf16 + partial gating ----
  float* wg_lds = (float*)smem;          // [N_EXP][CHK]
  const int c  = blockIdx.x >> 8;        // chunk 0..3
  const int bx = blockIdx.x & 255;       // token block (32 tokens)
  const int d0 = c * CHK;

  for (int f = tid; f < CHK * N_EXP / 4; f += 256) {
    const float4 v = ((const float4*)(Wg + (size_t)d0 * N_EXP))[f];
    const int dl = f >> 1;
    const int nh = (f & 1) * 4;
    wg_lds[(nh + 0) * CHK + dl] = v.x;
    wg_lds[(nh + 1) * CHK + dl] = v.y;
    wg_lds[(nh + 2) * CHK + dl] = v.z;
    wg_lds[(nh + 3) * CHK + dl] = v.w;
  }
  __syncthreads();

  const int lane = tid & 63;
  const int wv   = tid >> 6;

  for (int g = 0; g < 2; ++g) {
    const int t0 = bx * 32 + g * 16 + wv * 4;

    const float* xr0 = x + (size_t)(t0 + 0) * D_DIM + d0;
    const float* xr1 = x + (size_t)(t0 + 1) * D_DIM + d0;
    const float* xr2 = x + (size_t)(t0 + 2) * D_DIM + d0;
    const float* xr3 = x + (size_t)(t0 + 3) * D_DIM + d0;
    unsigned short* xw0 = xb + (size_t)(t0 + 0) * D_DIM + d0;
    unsigned short* xw1 = xb + (size_t)(t0 + 1) * D_DIM + d0;
    unsigned short* xw2 = xb + (size_t)(t0 + 2) * D_DIM + d0;
    unsigned short* xw3 = xb + (size_t)(t0 + 3) * D_DIM + d0;

    float acc[4][N_EXP];
#pragma unroll
    for (int t = 0; t < 4; ++t)
#pragma unroll
      for (int n = 0; n < N_EXP; ++n) acc[t][n] = 0.f;

#pragma unroll
    for (int s = 0; s < CHK / 256; ++s) {
      const int dl = s * 256 + lane * 4;
      float4 xv0 = *(const float4*)(xr0 + dl);
      float4 xv1 = *(const float4*)(xr1 + dl);
      float4 xv2 = *(const float4*)(xr2 + dl);
      float4 xv3 = *(const float4*)(xr3 + dl);
      float4 w4[N_EXP];
#pragma unroll
      for (int n = 0; n < N_EXP; ++n)
        w4[n] = *(const float4*)(wg_lds + n * CHK + dl);
      ushort4 p;
      p.x = f2bf(xv0.x); p.y = f2bf(xv0.y); p.z = f2bf(xv0.z); p.w = f2bf(xv0.w);
      *(ushort4*)(xw0 + dl) = p;
      p.x = f2bf(xv1.x); p.y = f2bf(xv1.y); p.z = f2bf(xv1.z); p.w = f2bf(xv1.w);
      *(ushort4*)(xw1 + dl) = p;
      p.x = f2bf(xv2.x); p.y = f2bf(xv2.y); p.z = f2bf(xv2.z); p.w = f2bf(xv2.w);
      *(ushort4*)(xw2 + dl) = p;
      p.x = f2bf(xv3.x); p.y = f2bf(xv3.y); p.z = f2bf(xv3.z); p.w = f2bf(xv3.w);
      *(ushort4*)(xw3 + dl) = p;
#pragma unroll
      for (int n = 0; n < N_EXP; ++n) {
        acc[0][n] = fmaf(xv0.x, w4[n].x, acc[0][n]);
        acc[0][n] = fmaf(xv0.y, w4[n].y, acc[0][n]);
        acc[0][n] = fmaf(xv0.z, w4[n].z, acc[0][n]);
        acc[0][n] = fmaf(xv0.w, w4[n].w, acc[0][n]);
        acc[1][n] = fmaf(xv1.x, w4[n].x, acc[1][n]);
        acc[1][n] = fmaf(xv1.y, w4[n].y, acc[1][n]);
        acc[1][n] = fmaf(xv1.z, w4[n].z, acc[1][n]);
        acc[1][n] = fmaf(xv1.w, w4[n].w, acc[1][n]);
        acc[2][n] = fmaf(xv2.x, w4[n].x, acc[2][n]);
        acc[2][n] = fmaf(xv2.y, w4[n].y, acc[2][n]);
        acc[2][n] = fmaf(xv2.z, w4[n].z, acc[2][n]);
        acc[2][n] = fmaf(xv2.w, w4[n].w, acc[2][n]);
        acc[3][n] = fmaf(xv3.x, w4[n].x, acc[3][n]);
        acc[3][n] = fmaf(xv3.y, w4[n].y, acc[3][n]);
        acc[3][n] = fmaf(xv3.z, w4[n].z, acc[3][n]);
        acc[3][n] = fmaf(xv3.w, w4[n].w, acc[3][n]);
      }
    }

#pragma unroll
    for (int t = 0; t < 4; ++t)
#pragma unroll
      for (int n = 0; n < N_EXP; ++n) {
#pragma unroll
        for (int off = 32; off > 0; off >>= 1)
          acc[t][n] += __shfl_xor(acc[t][n], off, 64);
      }
    if (lane == 0) {
#pragma unroll
      for (int t = 0; t < 4; ++t) {
        float* gp = gpart + ((size_t)c * B_TOK + (t0 + t)) * N_EXP;
        *(float4*)(gp)     = make_float4(acc[t][0], acc[t][1], acc[t][2], acc[t][3]);
        *(float4*)(gp + 4) = make_float4(acc[t][4], acc[t][5], acc[t][6], acc[t][7]);
      }
    }
  }
}

// ---------------- K1c: sum partials, top-2 + softmax, counts + tlist + per-slot weights ----------------
__global__ __launch_bounds__(256) void k1c_topk(
    const float* __restrict__ gpart, const float* __restrict__ bg,
    int* __restrict__ cnt, int* __restrict__ tlist, float* __restrict__ wslot) {
  __shared__ int lcnt[N_EXP], gbase[N_EXP];
  __shared__ float bgs[N_EXP];
  const int tid = threadIdx.x;
  if (tid < N_EXP) { lcnt[tid] = 0; bgs[tid] = bg[tid]; }
  __syncthreads();
  const int t = blockIdx.x * 256 + tid;

  float g[N_EXP];
#pragma unroll
  for (int n = 0; n < N_EXP; ++n) g[n] = bgs[n];
#pragma unroll
  for (int c = 0; c < NCHK; ++c) {
    const float* gp = gpart + ((size_t)c * B_TOK + t) * N_EXP;
    float4 a = *(const float4*)(gp);
    float4 b = *(const float4*)(gp + 4);
    g[0] += a.x; g[1] += a.y; g[2] += a.z; g[3] += a.w;
    g[4] += b.x; g[5] += b.y; g[6] += b.z; g[7] += b.w;
  }
  int i0 = 0;
#pragma unroll
  for (int n = 1; n < N_EXP; ++n) if (g[n] > g[i0]) i0 = n;
  int i1 = (i0 == 0) ? 1 : 0;
#pragma unroll
  for (int n = 0; n < N_EXP; ++n) if (n != i0 && g[n] > g[i1]) i1 = n;
  const float e1 = expf(g[i1] - g[i0]);
  const float inv = 1.f / (1.f + e1);
  const int lp0 = atomicAdd(&lcnt[i0], 1);
  const int lp1 = atomicAdd(&lcnt[i1], 1);
  __syncthreads();
  if (tid < N_EXP) gbase[tid] = atomicAdd(&cnt[tid], lcnt[tid]);
  __syncthreads();
  int p0 = gbase[i0] + lp0; p0 = p0 < ESTRIDE ? p0 : ESTRIDE - 1;
  int p1 = gbase[i1] + lp1; p1 = p1 < ESTRIDE ? p1 : ESTRIDE - 1;
  tlist[i0 * ESTRIDE + p0] = t;
  tlist[i1 * ESTRIDE + p1] = t;
  wslot[i0 * ESTRIDE + p0] = inv;
  wslot[i1 * ESTRIDE + p1] = e1 * inv;
}

// ---------------- K2: sparse per-expert h=relu(x@W1+b1); y=h@W2+b2 -> atomicAdd into out ----------------
// BK=128 dbuf. LDS rows are 256B (bank-degenerate), so blocks are stored with a
// rotate-by-row swizzle: block b of row r lives at position (b + r) mod 16.
// The rotation is applied to each lane's GLOBAL column offset (wave-uniform LDS
// base preserved for global_load_lds); reads apply the inverse -> conflict-free.
// Epilogue 2 weights each row's y by its routing weight and atomically adds into
// out[t] (exactly 2 adds per output element; commutative -> deterministic).
__global__ __launch_bounds__(256) void k2_experts(
    const unsigned short* __restrict__ xb,    // [B][D] bf16
    const unsigned short* __restrict__ w1t,   // [N][H][D] bf16
    const float* __restrict__ b1,             // [N][H]
    const float* __restrict__ W2,             // [N][H][O]
    const float* __restrict__ b2,             // [N][O]
    const int* __restrict__ cnt, const int* __restrict__ tlist,
    const float* __restrict__ wslot,
    float* __restrict__ out) {                // [B][O], pre-zeroed
  const int e    = blockIdx.y;
  int n_e        = cnt[e];
  n_e            = n_e < ESTRIDE ? n_e : ESTRIDE;
  const int row0 = blockIdx.x * BM;
  if (row0 >= n_e) return;

  __shared__ __align__(16) unsigned short sm[65536 + 2048];
  unsigned short* h_lds   = sm;
  unsigned short* w2t_lds = sm + 65536;

  const int tid  = threadIdx.x;
  const int lane = tid & 63;
  const int wv   = tid >> 6;
  const int quad = lane >> 4;
  const int cl   = lane & 15;

  // staging bases: lane (quad, cl) stages row j*4+quad, global block (cl - (j*4+quad)) & 15
  const unsigned short* Abase[8];
  const unsigned short* Bbase[8];
#pragma unroll
  for (int j = 0; j < 8; ++j) {
    const int rloc = wv * 32 + j * 4 + quad;
    int gr = row0 + rloc;
    gr = gr < n_e ? gr : n_e - 1;
    const int koff = ((cl - (j * 4 + quad)) & 15) * 8;
    Abase[j] = xb + (size_t)tlist[e * ESTRIDE + gr] * D_DIM + koff;
    Bbase[j] = w1t + ((size_t)e * H_DIM + rloc) * D_DIM + koff;
  }

#define STAGE(it, pp)                                                     \
  {                                                                       \
    const int ko = (it) * BK2;                                            \
    unsigned short* abuf = sm + (pp) * 32768;                             \
    unsigned short* bbuf = sm + 16384 + (pp) * 32768;                     \
    _Pragma("unroll")                                                     \
    for (int j = 0; j < 8; ++j) {                                         \
      const int ldsrow = (wv * 32 + j * 4) * BK2;                         \
      async16(Abase[j] + ko, abuf + ldsrow);                              \
      async16(Bbase[j] + ko, bbuf + ldsrow);                              \
    }                                                                     \
  }

  STAGE(0, 0);

  // stage W2^T swizzled: element (o, hh) -> o*128 + (((hh>>3)+o)&15)*8 + (hh&7)
  const float* W2e = W2 + (size_t)e * H_DIM * O_DIM;
  for (int idx = tid; idx < 16 * 128; idx += 256) {
    const int o = idx >> 7, hh = idx & 127;
    const float v = (o < O_DIM) ? W2e[hh * O_DIM + o] : 0.f;
    w2t_lds[o * 128 + ((((hh >> 3) + o) & 15) * 8) + (hh & 7)] = f2bf(v);
  }

  const int mhalf = (wv >> 1) * 64;
  const int nhalf = (wv & 1) * 64;

  f32x4 acc[4][4];
#pragma unroll
  for (int i = 0; i < 4; ++i)
#pragma unroll
    for (int j = 0; j < 4; ++j)
      acc[i][j] = (f32x4){0.f, 0.f, 0.f, 0.f};

  const int NIT = D_DIM / BK2;  // 24
  for (int it = 0; it < NIT; ++it) {
    __syncthreads();
    if (it + 1 < NIT) STAGE(it + 1, (it + 1) & 1);
    const unsigned short* al = sm + (it & 1) * 32768;
    const unsigned short* bl = sm + 16384 + (it & 1) * 32768;
#pragma unroll
    for (int kk = 0; kk < 4; ++kk) {
      const int pos = ((kk * 4 + quad + cl) & 15) * 8;  // swizzled k-block
      bf16x8 af[4], bfr[4];
#pragma unroll
      for (int mi = 0; mi < 4; ++mi)
        af[mi] = *(const bf16x8*)(al + (mhalf + mi * 16 + cl) * BK2 + pos);
#pragma unroll
      for (int ni = 0; ni < 4; ++ni)
        bfr[ni] = *(const bf16x8*)(bl + (nhalf + ni * 16 + cl) * BK2 + pos);
#pragma unroll
      for (int mi = 0; mi < 4; ++mi)
#pragma unroll
        for (int ni = 0; ni < 4; ++ni)
          acc[mi][ni] = __builtin_amdgcn_mfma_f32_16x16x32_bf16(af[mi], bfr[ni], acc[mi][ni], 0, 0, 0);
    }
  }
  __syncthreads();

  // epilogue 1: h = relu(acc + b1) -> h_lds (bf16). C/D layout: col=lane&15, row=quad*4+r
  const float* b1e = b1 + e * H_DIM;
#pragma unroll
  for (int ni = 0; ni < 4; ++ni) {
    const int col  = nhalf + ni * 16 + cl;
    const float bias = b1e[col];
#pragma unroll
    for (int mi = 0; mi < 4; ++mi) {
      const int rbase = mhalf + mi * 16 + (quad << 2);
#pragma unroll
      for (int r = 0; r < 4; ++r) {
        float v = acc[mi][ni][r] + bias;
        v = v > 0.f ? v : 0.f;
        h_lds[(rbase + r) * HLDS_STRIDE + col] = f2bf(v);
      }
    }
  }
  __syncthreads();

  // epilogue 2: y[128x16] = h[128x128] @ W2[128x16]; weighted atomic combine
  f32x4 acc2[2];
  acc2[0] = (f32x4){0.f, 0.f, 0.f, 0.f};
  acc2[1] = (f32x4){0.f, 0.f, 0.f, 0.f};
#pragma unroll
  for (int ks = 0; ks < 4; ++ks) {
    const int krd = ks * 32 + quad * 8;
    bf16x8 bfr = *(const bf16x8*)(w2t_lds + cl * 128 + ((ks * 4 + quad + cl) & 15) * 8);
#pragma unroll
    for (int mi = 0; mi < 2; ++mi) {
      bf16x8 afr = *(const bf16x8*)(h_lds + (wv * 32 + mi * 16 + cl) * HLDS_STRIDE + krd);
      acc2[mi] = __builtin_amdgcn_mfma_f32_16x16x32_bf16(afr, bfr, acc2[mi], 0, 0, 0);
    }
  }
  const int o = cl;
  if (o < O_DIM) {
    const float bias2 = b2[e * O_DIM + o];
#pragma unroll
    for (int mi = 0; mi < 2; ++mi) {
#pragma unroll
      for (int r = 0; r < 4; ++r) {
        const int rl = wv * 32 + mi * 16 + (quad << 2) + r;
        const int slot = row0 + rl;
        if (slot < n_e) {
          const int t = tlist[e * ESTRIDE + slot];
          const float w = wslot[e * ESTRIDE + slot];
          atomicAdd(out + (size_t)t * O_DIM + o, w * (acc2[mi][r] + bias2));
        }
      }
    }
  }
}

extern "C" void kernel_launch(void* const* d_in, const int* in_sizes, int n_in,
                              void* d_out, int out_size, void* d_ws, size_t ws_size,
                              hipStream_t stream) {
  const float* x  = (const float*)d_in[0];
  const float* Wg = (const float*)d_in[1];
  const float* bg = (const float*)d_in[2];
  const float* W1 = (const float*)d_in[3];
  const float* b1 = (const float*)d_in[4];
  const float* W2 = (const float*)d_in[5];
  const float* b2 = (const float*)d_in[6];
  float* out = (float*)d_out;

  char* ws = (char*)d_ws;
  unsigned short* xb  = (unsigned short*)ws;                 // 50331648 B
  unsigned short* w1t = (unsigned short*)(ws + 50331648);    // 6291456 B
  int*    cnt   = (int*)   (ws + 56623104);                  // 128 B
  int*    tlist = (int*)   (ws + 56623232);                  // 131072 B (8*4096*4)
  float*  wslot = (float*) (ws + 56754304);                  // 131072 B
  float*  gpart = (float*) (ws + 56885376);                  // 1048576 B
                                                             // total ~57.9 MB

  (void)hipMemsetAsync(cnt, 0, N_EXP * sizeof(int), stream);
  (void)hipMemsetAsync(out, 0, (size_t)B_TOK * O_DIM * sizeof(float), stream);
  k01_fused<<<dim3(K1A_BLOCKS + K0_BLOCKS), dim3(256), 0, stream>>>(
      x, Wg, xb, gpart, W1, w1t);
  k1c_topk<<<dim3(B_TOK / 256), dim3(256), 0, stream>>>(gpart, bg, cnt, tlist, wslot);
  k2_experts<<<dim3(ESTRIDE / BM, N_EXP), dim3(256), 0, stream>>>(
      xb, w1t, b1, W2, b2, cnt, tlist, wslot, out);
}

// Round 3
// 237.383 us; speedup vs baseline: 1.2576x; 1.2576x over previous
//
#include <hip/hip_runtime.h>
#include <hip/hip_bf16.h>

#define B_TOK 8192
#define D_DIM 3072
#define H_DIM 128
#define O_DIM 10
#define N_EXP 8

#define BM 128
#define BK2 128            // K-tile (24 iters over D=3072)
#define HLDS_STRIDE 136    // bf16 elems; row byte stride 272
#define CHK 768            // k1a D-chunk
#define NCHK 4
#define ESTRIDE 4096       // static slots per expert (>25 sigma above mean 2048)

typedef __bf16 bf16x8 __attribute__((ext_vector_type(8)));
typedef float  f32x4  __attribute__((ext_vector_type(4)));
typedef unsigned short us8 __attribute__((ext_vector_type(8)));

// fp32 -> bf16 round-to-nearest-even
__device__ __forceinline__ unsigned short f2bf(float f) {
  unsigned int u = __float_as_uint(f);
  unsigned int r = (u + 0x7FFFu + ((u >> 16) & 1u)) >> 16;
  return (unsigned short)r;
}

__device__ __forceinline__ void async16(const void* g, void* l) {
  __builtin_amdgcn_global_load_lds(
      (const __attribute__((address_space(1))) void*)g,
      (__attribute__((address_space(3))) void*)l,
      16, 0, 0);
}

// ---------------- K0: W1 [8][3072][128] fp32 -> W1^T [8][128][3072] bf16 ----------------
__global__ __launch_bounds__(256) void k0_w1_transpose(const float* __restrict__ W1,
                                                       unsigned short* __restrict__ w1t) {
  __shared__ __align__(16) unsigned short lds[64 * 72];  // [h][72]
  const int e  = blockIdx.z;
  const int d0 = blockIdx.x * 64;
  const int h0 = blockIdx.y * 64;
  const int tid = threadIdx.x;

  const float* src = W1 + ((size_t)e * D_DIM + d0) * H_DIM + h0;
  const int hl = tid & 63;   // h lane
  const int dg = tid >> 6;   // 0..3
#pragma unroll
  for (int k = 0; k < 16; ++k) {
    const int d = dg + 4 * k;
    lds[hl * 72 + d] = f2bf(src[(size_t)d * H_DIM + hl]);
  }
  __syncthreads();

  unsigned short* dst = w1t + ((size_t)e * H_DIM + h0) * D_DIM + d0;
  const int q  = tid & 7;    // d-oct
  const int h1 = tid >> 3;   // 0..31
#pragma unroll
  for (int k = 0; k < 2; ++k) {
    const int h = h1 + 32 * k;
    const int d = q * 8;
    us8 v = *(const us8*)(lds + h * 72 + d);
    *(us8*)(dst + (size_t)h * D_DIM + d) = v;
  }
}

// ---------------- K1a: stream x -> bf16 + partial gating per D-chunk ----------------
// No LDS, no barrier: each lane's Wg slice (4 d-rows x 8 experts = 32 contiguous
// floats) is exactly one 128-B line -> first float4 load pulls it into L1, the
// other 7 hit L1. Wg (96 KB) stays L2-hot. Blocks are pure independent streamers.
__global__ __launch_bounds__(256) void k1a_stream(
    const float* __restrict__ x, const float* __restrict__ Wg,
    unsigned short* __restrict__ xb, float* __restrict__ gpart) {
  const int c   = blockIdx.y;
  const int d0  = c * CHK;
  const int tid = threadIdx.x;
  const int lane = tid & 63;
  const int wv   = tid >> 6;
  const int t0   = blockIdx.x * 16 + wv * 4;

  const float* xr0 = x + (size_t)(t0 + 0) * D_DIM + d0;
  const float* xr1 = x + (size_t)(t0 + 1) * D_DIM + d0;
  const float* xr2 = x + (size_t)(t0 + 2) * D_DIM + d0;
  const float* xr3 = x + (size_t)(t0 + 3) * D_DIM + d0;
  unsigned short* xw0 = xb + (size_t)(t0 + 0) * D_DIM + d0;
  unsigned short* xw1 = xb + (size_t)(t0 + 1) * D_DIM + d0;
  unsigned short* xw2 = xb + (size_t)(t0 + 2) * D_DIM + d0;
  unsigned short* xw3 = xb + (size_t)(t0 + 3) * D_DIM + d0;

  float acc[4][N_EXP];
#pragma unroll
  for (int t = 0; t < 4; ++t)
#pragma unroll
    for (int n = 0; n < N_EXP; ++n) acc[t][n] = 0.f;

#pragma unroll
  for (int s = 0; s < CHK / 256; ++s) {
    const int dl = s * 256 + lane * 4;
    float4 xv0 = *(const float4*)(xr0 + dl);
    float4 xv1 = *(const float4*)(xr1 + dl);
    float4 xv2 = *(const float4*)(xr2 + dl);
    float4 xv3 = *(const float4*)(xr3 + dl);
    // Wg rows d0+dl .. d0+dl+3: 32 contiguous floats (one line per lane)
    const float4* wp = (const float4*)(Wg + (size_t)(d0 + dl) * N_EXP);
    float4 wa[4], wb[4];
#pragma unroll
    for (int j = 0; j < 4; ++j) { wa[j] = wp[2 * j]; wb[j] = wp[2 * j + 1]; }

    ushort4 p;
    p.x = f2bf(xv0.x); p.y = f2bf(xv0.y); p.z = f2bf(xv0.z); p.w = f2bf(xv0.w);
    *(ushort4*)(xw0 + dl) = p;
    p.x = f2bf(xv1.x); p.y = f2bf(xv1.y); p.z = f2bf(xv1.z); p.w = f2bf(xv1.w);
    *(ushort4*)(xw1 + dl) = p;
    p.x = f2bf(xv2.x); p.y = f2bf(xv2.y); p.z = f2bf(xv2.z); p.w = f2bf(xv2.w);
    *(ushort4*)(xw2 + dl) = p;
    p.x = f2bf(xv3.x); p.y = f2bf(xv3.y); p.z = f2bf(xv3.z); p.w = f2bf(xv3.w);
    *(ushort4*)(xw3 + dl) = p;

    float xe0[4] = {xv0.x, xv0.y, xv0.z, xv0.w};
    float xe1[4] = {xv1.x, xv1.y, xv1.z, xv1.w};
    float xe2[4] = {xv2.x, xv2.y, xv2.z, xv2.w};
    float xe3[4] = {xv3.x, xv3.y, xv3.z, xv3.w};
#pragma unroll
    for (int j = 0; j < 4; ++j) {
      acc[0][0] = fmaf(xe0[j], wa[j].x, acc[0][0]);
      acc[0][1] = fmaf(xe0[j], wa[j].y, acc[0][1]);
      acc[0][2] = fmaf(xe0[j], wa[j].z, acc[0][2]);
      acc[0][3] = fmaf(xe0[j], wa[j].w, acc[0][3]);
      acc[0][4] = fmaf(xe0[j], wb[j].x, acc[0][4]);
      acc[0][5] = fmaf(xe0[j], wb[j].y, acc[0][5]);
      acc[0][6] = fmaf(xe0[j], wb[j].z, acc[0][6]);
      acc[0][7] = fmaf(xe0[j], wb[j].w, acc[0][7]);
      acc[1][0] = fmaf(xe1[j], wa[j].x, acc[1][0]);
      acc[1][1] = fmaf(xe1[j], wa[j].y, acc[1][1]);
      acc[1][2] = fmaf(xe1[j], wa[j].z, acc[1][2]);
      acc[1][3] = fmaf(xe1[j], wa[j].w, acc[1][3]);
      acc[1][4] = fmaf(xe1[j], wb[j].x, acc[1][4]);
      acc[1][5] = fmaf(xe1[j], wb[j].y, acc[1][5]);
      acc[1][6] = fmaf(xe1[j], wb[j].z, acc[1][6]);
      acc[1][7] = fmaf(xe1[j], wb[j].w, acc[1][7]);
      acc[2][0] = fmaf(xe2[j], wa[j].x, acc[2][0]);
      acc[2][1] = fmaf(xe2[j], wa[j].y, acc[2][1]);
      acc[2][2] = fmaf(xe2[j], wa[j].z, acc[2][2]);
      acc[2][3] = fmaf(xe2[j], wa[j].w, acc[2][3]);
      acc[2][4] = fmaf(xe2[j], wb[j].x, acc[2][4]);
      acc[2][5] = fmaf(xe2[j], wb[j].y, acc[2][5]);
      acc[2][6] = fmaf(xe2[j], wb[j].z, acc[2][6]);
      acc[2][7] = fmaf(xe2[j], wb[j].w, acc[2][7]);
      acc[3][0] = fmaf(xe3[j], wa[j].x, acc[3][0]);
      acc[3][1] = fmaf(xe3[j], wa[j].y, acc[3][1]);
      acc[3][2] = fmaf(xe3[j], wa[j].z, acc[3][2]);
      acc[3][3] = fmaf(xe3[j], wa[j].w, acc[3][3]);
      acc[3][4] = fmaf(xe3[j], wb[j].x, acc[3][4]);
      acc[3][5] = fmaf(xe3[j], wb[j].y, acc[3][5]);
      acc[3][6] = fmaf(xe3[j], wb[j].z, acc[3][6]);
      acc[3][7] = fmaf(xe3[j], wb[j].w, acc[3][7]);
    }
  }

#pragma unroll
  for (int t = 0; t < 4; ++t)
#pragma unroll
    for (int n = 0; n < N_EXP; ++n) {
#pragma unroll
      for (int off = 32; off > 0; off >>= 1)
        acc[t][n] += __shfl_xor(acc[t][n], off, 64);
    }
  if (lane == 0) {
#pragma unroll
    for (int t = 0; t < 4; ++t) {
      float* gp = gpart + ((size_t)c * B_TOK + (t0 + t)) * N_EXP;
      *(float4*)(gp)     = make_float4(acc[t][0], acc[t][1], acc[t][2], acc[t][3]);
      *(float4*)(gp + 4) = make_float4(acc[t][4], acc[t][5], acc[t][6], acc[t][7]);
    }
  }
}

// ---------------- K1c: sum partials, top-2 + softmax, counts + DIRECT tlist write ----------------
// Static expert regions (ESTRIDE slots each) -> no scan/scatter kernels needed.
__global__ __launch_bounds__(256) void k1c_topk(
    const float* __restrict__ gpart, const float* __restrict__ bg,
    int4* __restrict__ idx4, float2* __restrict__ wts, int* __restrict__ cnt,
    int* __restrict__ tlist) {
  __shared__ int lcnt[N_EXP], gbase[N_EXP];
  __shared__ float bgs[N_EXP];
  const int tid = threadIdx.x;
  if (tid < N_EXP) { lcnt[tid] = 0; bgs[tid] = bg[tid]; }
  __syncthreads();
  const int t = blockIdx.x * 256 + tid;

  float g[N_EXP];
#pragma unroll
  for (int n = 0; n < N_EXP; ++n) g[n] = bgs[n];
#pragma unroll
  for (int c = 0; c < NCHK; ++c) {
    const float* gp = gpart + ((size_t)c * B_TOK + t) * N_EXP;
    float4 a = *(const float4*)(gp);
    float4 b = *(const float4*)(gp + 4);
    g[0] += a.x; g[1] += a.y; g[2] += a.z; g[3] += a.w;
    g[4] += b.x; g[5] += b.y; g[6] += b.z; g[7] += b.w;
  }
  int i0 = 0;
#pragma unroll
  for (int n = 1; n < N_EXP; ++n) if (g[n] > g[i0]) i0 = n;
  int i1 = (i0 == 0) ? 1 : 0;
#pragma unroll
  for (int n = 0; n < N_EXP; ++n) if (n != i0 && g[n] > g[i1]) i1 = n;
  const float e1 = expf(g[i1] - g[i0]);
  const float inv = 1.f / (1.f + e1);
  const int lp0 = atomicAdd(&lcnt[i0], 1);
  const int lp1 = atomicAdd(&lcnt[i1], 1);
  __syncthreads();
  if (tid < N_EXP) gbase[tid] = atomicAdd(&cnt[tid], lcnt[tid]);
  __syncthreads();
  int p0 = gbase[i0] + lp0; p0 = p0 < ESTRIDE ? p0 : ESTRIDE - 1;
  int p1 = gbase[i1] + lp1; p1 = p1 < ESTRIDE ? p1 : ESTRIDE - 1;
  tlist[i0 * ESTRIDE + p0] = t;
  tlist[i1 * ESTRIDE + p1] = t;
  idx4[t] = make_int4(i0, p0, i1, p1);
  wts[t]  = make_float2(inv, e1 * inv);
}

// ---------------- K2: sparse per-expert h=relu(x@W1+b1); y=h@W2+b2 -> ypair ----------------
// BK=128 dbuf. LDS rows are 256B (bank-degenerate), so blocks are stored with a
// rotate-by-row swizzle: block b of row r lives at position (b + r) mod 16.
// The rotation is applied to each lane's GLOBAL column offset (wave-uniform LDS
// base preserved for global_load_lds); reads apply the inverse -> conflict-free.
__global__ __launch_bounds__(256) void k2_experts(
    const unsigned short* __restrict__ xb,    // [B][D] bf16
    const unsigned short* __restrict__ w1t,   // [N][H][D] bf16
    const float* __restrict__ b1,             // [N][H]
    const float* __restrict__ W2,             // [N][H][O]
    const float* __restrict__ b2,             // [N][O]
    const int* __restrict__ cnt, const int* __restrict__ tlist,
    float* __restrict__ ypair) {              // [N*ESTRIDE][16]
  const int e    = blockIdx.y;
  int n_e        = cnt[e];
  n_e            = n_e < ESTRIDE ? n_e : ESTRIDE;
  const int row0 = blockIdx.x * BM;
  if (row0 >= n_e) return;

  __shared__ __align__(16) unsigned short sm[65536 + 2048];
  unsigned short* h_lds   = sm;
  unsigned short* w2t_lds = sm + 65536;

  const int tid  = threadIdx.x;
  const int lane = tid & 63;
  const int wv   = tid >> 6;
  const int quad = lane >> 4;
  const int cl   = lane & 15;

  // staging bases: lane (quad, cl) stages row j*4+quad, global block (cl - (j*4+quad)) & 15
  const unsigned short* Abase[8];
  const unsigned short* Bbase[8];
#pragma unroll
  for (int j = 0; j < 8; ++j) {
    const int rloc = wv * 32 + j * 4 + quad;
    int gr = row0 + rloc;
    gr = gr < n_e ? gr : n_e - 1;
    const int koff = ((cl - (j * 4 + quad)) & 15) * 8;
    Abase[j] = xb + (size_t)tlist[e * ESTRIDE + gr] * D_DIM + koff;
    Bbase[j] = w1t + ((size_t)e * H_DIM + rloc) * D_DIM + koff;
  }

#define STAGE(it, pp)                                                     \
  {                                                                       \
    const int ko = (it) * BK2;                                            \
    unsigned short* abuf = sm + (pp) * 32768;                             \
    unsigned short* bbuf = sm + 16384 + (pp) * 32768;                     \
    _Pragma("unroll")                                                     \
    for (int j = 0; j < 8; ++j) {                                         \
      const int ldsrow = (wv * 32 + j * 4) * BK2;                         \
      async16(Abase[j] + ko, abuf + ldsrow);                              \
      async16(Bbase[j] + ko, bbuf + ldsrow);                              \
    }                                                                     \
  }

  STAGE(0, 0);

  // stage W2^T swizzled: element (o, hh) -> o*128 + (((hh>>3)+o)&15)*8 + (hh&7)
  const float* W2e = W2 + (size_t)e * H_DIM * O_DIM;
  for (int idx = tid; idx < 16 * 128; idx += 256) {
    const int o = idx >> 7, hh = idx & 127;
    const float v = (o < O_DIM) ? W2e[hh * O_DIM + o] : 0.f;
    w2t_lds[o * 128 + ((((hh >> 3) + o) & 15) * 8) + (hh & 7)] = f2bf(v);
  }

  const int mhalf = (wv >> 1) * 64;
  const int nhalf = (wv & 1) * 64;

  f32x4 acc[4][4];
#pragma unroll
  for (int i = 0; i < 4; ++i)
#pragma unroll
    for (int j = 0; j < 4; ++j)
      acc[i][j] = (f32x4){0.f, 0.f, 0.f, 0.f};

  const int NIT = D_DIM / BK2;  // 24
  for (int it = 0; it < NIT; ++it) {
    __syncthreads();
    if (it + 1 < NIT) STAGE(it + 1, (it + 1) & 1);
    const unsigned short* al = sm + (it & 1) * 32768;
    const unsigned short* bl = sm + 16384 + (it & 1) * 32768;
#pragma unroll
    for (int kk = 0; kk < 4; ++kk) {
      const int pos = ((kk * 4 + quad + cl) & 15) * 8;  // swizzled k-block
      bf16x8 af[4], bfr[4];
#pragma unroll
      for (int mi = 0; mi < 4; ++mi)
        af[mi] = *(const bf16x8*)(al + (mhalf + mi * 16 + cl) * BK2 + pos);
#pragma unroll
      for (int ni = 0; ni < 4; ++ni)
        bfr[ni] = *(const bf16x8*)(bl + (nhalf + ni * 16 + cl) * BK2 + pos);
#pragma unroll
      for (int mi = 0; mi < 4; ++mi)
#pragma unroll
        for (int ni = 0; ni < 4; ++ni)
          acc[mi][ni] = __builtin_amdgcn_mfma_f32_16x16x32_bf16(af[mi], bfr[ni], acc[mi][ni], 0, 0, 0);
    }
  }
  __syncthreads();

  // epilogue 1: h = relu(acc + b1) -> h_lds (bf16). C/D layout: col=lane&15, row=quad*4+r
  const float* b1e = b1 + e * H_DIM;
#pragma unroll
  for (int ni = 0; ni < 4; ++ni) {
    const int col  = nhalf + ni * 16 + cl;
    const float bias = b1e[col];
#pragma unroll
    for (int mi = 0; mi < 4; ++mi) {
      const int rbase = mhalf + mi * 16 + (quad << 2);
#pragma unroll
      for (int r = 0; r < 4; ++r) {
        float v = acc[mi][ni][r] + bias;
        v = v > 0.f ? v : 0.f;
        h_lds[(rbase + r) * HLDS_STRIDE + col] = f2bf(v);
      }
    }
  }
  __syncthreads();

  // epilogue 2: y[128x16] = h[128x128] @ W2[128x16]
  f32x4 acc2[2];
  acc2[0] = (f32x4){0.f, 0.f, 0.f, 0.f};
  acc2[1] = (f32x4){0.f, 0.f, 0.f, 0.f};
#pragma unroll
  for (int ks = 0; ks < 4; ++ks) {
    const int krd = ks * 32 + quad * 8;
    bf16x8 bfr = *(const bf16x8*)(w2t_lds + cl * 128 + ((ks * 4 + quad + cl) & 15) * 8);
#pragma unroll
    for (int mi = 0; mi < 2; ++mi) {
      bf16x8 afr = *(const bf16x8*)(h_lds + (wv * 32 + mi * 16 + cl) * HLDS_STRIDE + krd);
      acc2[mi] = __builtin_amdgcn_mfma_f32_16x16x32_bf16(afr, bfr, acc2[mi], 0, 0, 0);
    }
  }
  const int o = cl;
  if (o < O_DIM) {
    const float bias2 = b2[e * O_DIM + o];
#pragma unroll
    for (int mi = 0; mi < 2; ++mi) {
#pragma unroll
      for (int r = 0; r < 4; ++r) {
        const int rl = wv * 32 + mi * 16 + (quad << 2) + r;
        if (row0 + rl < n_e)
          ypair[(size_t)(e * ESTRIDE + row0 + rl) * 16 + o] = acc2[mi][r] + bias2;
      }
    }
  }
}

// ---------------- K3: combine top-2 via static slots ----------------
__global__ __launch_bounds__(256) void k3_combine(
    const float* __restrict__ ypair, const int4* __restrict__ idx4,
    const float2* __restrict__ wts, float* __restrict__ out) {
  const int g = blockIdx.x * 256 + threadIdx.x;
  if (g >= B_TOK * O_DIM) return;
  const int b = g / O_DIM, o = g - b * O_DIM;
  const int4 r = idx4[b];
  const float2 w = wts[b];
  out[g] = w.x * ypair[(size_t)(r.x * ESTRIDE + r.y) * 16 + o] +
           w.y * ypair[(size_t)(r.z * ESTRIDE + r.w) * 16 + o];
}

extern "C" void kernel_launch(void* const* d_in, const int* in_sizes, int n_in,
                              void* d_out, int out_size, void* d_ws, size_t ws_size,
                              hipStream_t stream) {
  const float* x  = (const float*)d_in[0];
  const float* Wg = (const float*)d_in[1];
  const float* bg = (const float*)d_in[2];
  const float* W1 = (const float*)d_in[3];
  const float* b1 = (const float*)d_in[4];
  const float* W2 = (const float*)d_in[5];
  const float* b2 = (const float*)d_in[6];
  float* out = (float*)d_out;

  char* ws = (char*)d_ws;
  unsigned short* xb  = (unsigned short*)ws;                 // 50331648 B
  unsigned short* w1t = (unsigned short*)(ws + 50331648);    // 6291456 B
  int4*   idx4  = (int4*)  (ws + 56623104);                  // 131072 B
  float2* wts   = (float2*)(ws + 56754176);                  // 65536 B
  int*    cnt   = (int*)   (ws + 56819712);                  // 128 B
  int*    tlist = (int*)   (ws + 56819840);                  // 131072 B (8*4096*4)
  // gpart (1 MB) overlays ypair: gpart dead after k1c; ypair written by k2 (after).
  float*  gpart = (float*) (ws + 56950912);
  float*  ypair = (float*) (ws + 56950912);                  // 2097152 B (8*4096*16*4)
                                                             // total ~59.05 MB

  k0_w1_transpose<<<dim3(48, 2, 8), dim3(256), 0, stream>>>(W1, w1t);
  (void)hipMemsetAsync(cnt, 0, N_EXP * sizeof(int), stream);
  k1a_stream<<<dim3(B_TOK / 16, NCHK), dim3(256), 0, stream>>>(x, Wg, xb, gpart);
  k1c_topk<<<dim3(B_TOK / 256), dim3(256), 0, stream>>>(gpart, bg, idx4, wts, cnt, tlist);
  k2_experts<<<dim3(ESTRIDE / BM, N_EXP), dim3(256), 0, stream>>>(
      xb, w1t, b1, W2, b2, cnt, tlist, ypair);
  k3_combine<<<dim3((B_TOK * O_DIM + 255) / 256), dim3(256), 0, stream>>>(
      ypair, idx4, wts, out);
}